// Round 1
// baseline (130.929 us; speedup 1.0000x reference)
//
#include <hip/hip_runtime.h>
#include <stdint.h>

// B=8, C=64, N=4096. Flash attention with Q=K=x^T [N,64], V=x^T W [N,64].
// Round 6: software-pipelined K/V staging. Kt/Vt double-buffered (48 KB LDS,
// 3 blocks/CU); per iter: one __syncthreads (drains prev prefetch) -> issue
// next-tile global_load_lds -> compute current tile. Staging latency hides
// under the S^T/PV MFMA+exp phase instead of stalling at a barrier.
// exp moved to exp2-domain (fma+v_exp instead of add+mul+v_exp).

#define NTOK 4096
#define CCH  64

typedef float v4f __attribute__((ext_vector_type(4)));
typedef __bf16 v8bf __attribute__((ext_vector_type(8)));
typedef unsigned short v8us __attribute__((ext_vector_type(8)));

__device__ __forceinline__ unsigned short f2bf(float f) {
    union { float f; unsigned int u; } c; c.f = f;
    unsigned int r = c.u + 0x7fffu + ((c.u >> 16) & 1u);   // RNE
    return (unsigned short)(r >> 16);
}

__device__ __forceinline__ v8bf ld8(const unsigned short* p) {
    union { v8us s; v8bf b; } u;
    u.s = *(const v8us*)p;
    return u.b;
}

// pack two f32 -> u32 of (bf16_trunc(a) | bf16_trunc(b)<<16), one v_perm
__device__ __forceinline__ unsigned int pkbf(float a, float b) {
    union { float f; unsigned int u; } ua, ub; ua.f = a; ub.f = b;
    return __builtin_amdgcn_perm(ub.u, ua.u, 0x07060302u);
}

__device__ __forceinline__ float ex2(float x) {
#if __has_builtin(__builtin_amdgcn_exp2f)
    return __builtin_amdgcn_exp2f(x);
#else
    return exp2f(x);
#endif
}

// async global->LDS, 16B per lane; LDS dest = wave-uniform base + lane*16
__device__ __forceinline__ void gload_lds16(const void* g, void* l) {
    __builtin_amdgcn_global_load_lds(
        (const __attribute__((address_space(1))) unsigned int*)g,
        (__attribute__((address_space(3))) unsigned int*)l,
        16, 0, 0);
}

// ---------------------------------------------------------------------------
// Prep: xT[b][n][c] = bf16(x[b][c][n]);  sT[b][d][n] = bf16(sum_c x[b][c][n] W[c][d])
// Grid (64, 8) x 256. Block = 64 tokens. Wave wv owns d-range [wv*16, wv*16+16).
// ---------------------------------------------------------------------------
__global__ __launch_bounds__(256) void prep_kernel(
    const float* __restrict__ x,        // [8][64][4096]
    const float* __restrict__ w,        // [64][64]
    unsigned short* __restrict__ xT,    // [8][4096][64] bf16
    unsigned short* __restrict__ sT)    // [8][64][4096] bf16
{
    __shared__ float Xf[64 * 65];       // [c][n], stride 65 (bank-spread)

    const int tid  = threadIdx.x;
    const int lane = tid & 63;
    const int wv   = __builtin_amdgcn_readfirstlane(tid >> 6);  // wave-uniform
    const int b    = blockIdx.y;
    const int n0   = blockIdx.x * 64;

    // ---- stage x tile [64 c][64 n] f32 into LDS (coalesced global reads) ----
    const float* xb = x + (size_t)b * CCH * NTOK + n0 + lane;
    #pragma unroll
    for (int k = 0; k < 16; ++k) {
        const int c = wv * 16 + k;
        Xf[c * 65 + lane] = xb[(size_t)c * NTOK];
    }
    __syncthreads();

    // ---- write xT[n][c] bf16: thread -> n = tid>>2, c-chunk = (tid&3)*16 ----
    {
        const int n  = tid >> 2;
        const int c0 = (tid & 3) * 16;
        unsigned int pk[8];
        #pragma unroll
        for (int k = 0; k < 8; ++k) {
            const float a = Xf[(c0 + 2 * k) * 65 + n];
            const float c2 = Xf[(c0 + 2 * k + 1) * 65 + n];
            pk[k] = (unsigned int)f2bf(a) | ((unsigned int)f2bf(c2) << 16);
        }
        unsigned short* xtr = xT + ((size_t)b * NTOK + n0 + n) * CCH + c0;
        *(uint4*)(xtr)     = *(uint4*)(pk);
        *(uint4*)(xtr + 8) = *(uint4*)(pk + 4);
    }

    // ---- support: lane's token n0+lane, d in [wv*16, wv*16+16) ----
    float acc[16];
    #pragma unroll
    for (int d = 0; d < 16; ++d) acc[d] = 0.f;

    #pragma unroll 4
    for (int c = 0; c < 64; ++c) {
        const float xc = Xf[c * 65 + lane];
        const float* wr = w + c * 64 + wv * 16;      // scalar address -> s_load
        #pragma unroll
        for (int d = 0; d < 16; ++d) acc[d] = fmaf(xc, wr[d], acc[d]);
    }
    unsigned short* stb = sT + (size_t)b * CCH * NTOK + n0 + lane;
    #pragma unroll
    for (int d = 0; d < 16; ++d)
        stb[(size_t)(wv * 16 + d) * NTOK] = f2bf(acc[d]);    // coalesced
}

// ---------------------------------------------------------------------------
// Flash chunk kernel. Grid: (32 i-tiles, KS chunks, 8 batches) x 256 thr.
// Block = 128 Q rows (32/wave, 2 m-tiles). j-tile = 64, K/V double-buffered.
// S^T = K·Q^T via mfma(K_frag, Q_frag): D[row=j_loc=quad*4+r][col=i_loc=l16].
// P^T stored in LDS [i][j] (stride 64, 8-short chunks at pos = chunk^(i&7)).
// O^T = V^T·P^T: D[row=d_loc][col=i_loc]; epilogue float4 per (m,ct).
// Pipeline per iter: sync (prev prefetch landed) -> issue prefetch(t+1) ->
// compute(t). Single barrier per iteration.
// ---------------------------------------------------------------------------
__global__ __launch_bounds__(256, 3) void flash_kernel(
    const unsigned short* __restrict__ xT,   // [8][4096][64]
    const unsigned short* __restrict__ sT,   // [8][64][4096]
    float* __restrict__ part_o,              // [8][KS][4096][64]
    float* __restrict__ part_l,              // [8][KS][4096]
    int nchunk, int chunk_len)
{
    __shared__ __align__(16) unsigned short Kt[2][64 * 64];  // 16 KB
    __shared__ __align__(16) unsigned short Vt[2][64 * 64];  // 16 KB
    __shared__ __align__(16) unsigned short Pt[4][32 * 64];  // 16 KB

    const int tid  = threadIdx.x;
    const int w    = tid >> 6;
    const int lane = tid & 63;
    const int quad = lane >> 4;
    const int l16  = lane & 15;
    const int l7   = l16 & 7;
    const int b     = blockIdx.z;
    const int chunk = blockIdx.y;
    const int i0   = blockIdx.x * 128;
    const int irow = i0 + w * 32;
    const int jb   = chunk * chunk_len;

    const unsigned short* xTb = xT + (size_t)b * NTOK * CCH;
    const unsigned short* sTb = sT + (size_t)b * CCH * NTOK;

    // staging geometry: lane stages row (s*32 + srow), swizzled chunk sc
    const int srow = w * 8 + (lane >> 3);          // 0..31
    const int sc   = (lane & 7) ^ (lane >> 3);     // global chunk to fetch

    auto stage = [&](int j0, int bf) {
        unsigned short* kd = Kt[bf] + w * 512;
        unsigned short* vd = Vt[bf] + w * 512;
        gload_lds16(xTb + (size_t)(j0 + srow) * CCH + sc * 8,       kd);
        gload_lds16(xTb + (size_t)(j0 + 32 + srow) * CCH + sc * 8,  kd + 2048);
        gload_lds16(sTb + (size_t)srow * NTOK + j0 + sc * 8,        vd);
        gload_lds16(sTb + (size_t)(32 + srow) * NTOK + j0 + sc * 8, vd + 2048);
    };

    // prologue: issue tile-0 staging before register setup (extra overlap)
    stage(jb, 0);

    // Q fragments (B-operand of S^T): lane holds Q[irow+m*16+l16][quad*8+..]
    v8bf aq0[2], aq1[2];
    #pragma unroll
    for (int m = 0; m < 2; ++m) {
        const unsigned short* qr = xTb + (size_t)(irow + m * 16 + l16) * CCH + quad * 8;
        aq0[m] = ld8(qr);
        aq1[m] = ld8(qr + 32);
    }

    // fixed stabilizer in log2 domain: negm2[m] = -||q_i||^2 * log2(e)
    const float L2E = 1.4426950408889634f;
    float negm2[2];
    #pragma unroll
    for (int m = 0; m < 2; ++m) {
        float msq = 0.f;
        #pragma unroll
        for (int i = 0; i < 8; ++i) {
            float e0 = (float)aq0[m][i], e1 = (float)aq1[m][i];
            msq = fmaf(e0, e0, msq);
            msq = fmaf(e1, e1, msq);
        }
        msq += __shfl_xor(msq, 16);
        msq += __shfl_xor(msq, 32);
        negm2[m] = -msq * L2E;
    }

    v4f o[2][4];        // o[m][ct]: O^T tile rows d=ct*16+quad*4+r, col i=m*16+l16
    #pragma unroll
    for (int m = 0; m < 2; ++m)
        #pragma unroll
        for (int ct = 0; ct < 4; ++ct) { o[m][ct][0]=0.f; o[m][ct][1]=0.f; o[m][ct][2]=0.f; o[m][ct][3]=0.f; }
    float rsum[2] = {0.f, 0.f};

    unsigned short* Pw = Pt[w];
    const int phalf = (quad & 1) * 4;              // 4-short half within chunk
    const int pgq   = quad >> 1;                   // chunk bit from quad

    int cur = 0;
    for (int jj = 0; jj < chunk_len; jj += 64) {
        // tile jj is staged in buf[cur]; rendezvous also proves all waves are
        // done reading buf[cur^1], so it is safe to restage it below.
        __syncthreads();
        if (jj + 64 < chunk_len)
            stage(jb + jj + 64, cur ^ 1);          // prefetch overlaps compute

        const unsigned short* Kc = Kt[cur];
        const unsigned short* Vc = Vt[cur];

        // ---- S^T = K Q^T, exp2, pack, b64-store P^T ----
        #pragma unroll
        for (int jt = 0; jt < 4; ++jt) {
            const int krow = 16 * jt + l16;
            const unsigned short* kb = Kc + krow * 64;
            const int c0 = quad ^ (krow & 7);
            v8bf bk0 = ld8(kb + c0 * 8);
            v8bf bk1 = ld8(kb + (c0 ^ 4) * 8);
            #pragma unroll
            for (int m = 0; m < 2; ++m) {
                v4f z; z[0]=0.f; z[1]=0.f; z[2]=0.f; z[3]=0.f;
                z = __builtin_amdgcn_mfma_f32_16x16x32_bf16(bk0, aq0[m], z, 0, 0, 0);
                z = __builtin_amdgcn_mfma_f32_16x16x32_bf16(bk1, aq1[m], z, 0, 0, 0);
                const float p0 = ex2(fmaf(z[0], L2E, negm2[m]));
                const float p1 = ex2(fmaf(z[1], L2E, negm2[m]));
                const float p2 = ex2(fmaf(z[2], L2E, negm2[m]));
                const float p3 = ex2(fmaf(z[3], L2E, negm2[m]));
                rsum[m] += (p0 + p1) + (p2 + p3);
                uint2 pk; pk.x = pkbf(p0, p1); pk.y = pkbf(p2, p3);
                // row i = m*16+l16; j = 16*jt + quad*4 + r -> chunk g=2jt+(quad>>1)
                const int pos = (2 * jt + pgq) ^ l7;
                *(uint2*)(Pw + (m * 16 + l16) * 64 + pos * 8 + phalf) = pk;
            }
        }

        // ---- P^T B-frags (wave-local; lgkmcnt ordering only) ----
        v8bf pb0[2], pb1[2];
        #pragma unroll
        for (int m = 0; m < 2; ++m) {
            const unsigned short* pr = Pw + (m * 16 + l16) * 64;
            const int p0c = quad ^ l7;
            pb0[m] = ld8(pr + p0c * 8);
            pb1[m] = ld8(pr + (p0c ^ 4) * 8);
        }

        // ---- O^T += V^T P^T ----
        #pragma unroll
        for (int ct = 0; ct < 4; ++ct) {
            const int vrow = 16 * ct + l16;
            const unsigned short* vb = Vc + vrow * 64;
            const int c0 = quad ^ (vrow & 7);
            v8bf bv0 = ld8(vb + c0 * 8);
            v8bf bv1 = ld8(vb + (c0 ^ 4) * 8);
            #pragma unroll
            for (int m = 0; m < 2; ++m) {
                o[m][ct] = __builtin_amdgcn_mfma_f32_16x16x32_bf16(bv0, pb0[m], o[m][ct], 0, 0, 0);
                o[m][ct] = __builtin_amdgcn_mfma_f32_16x16x32_bf16(bv1, pb1[m], o[m][ct], 0, 0, 0);
            }
        }
        cur ^= 1;
    }

    // ---- epilogue ----
    const size_t pbase = (size_t)(b * nchunk + chunk) * NTOK + irow;
    #pragma unroll
    for (int m = 0; m < 2; ++m) {
        float t = rsum[m];
        t += __shfl_xor(t, 16);
        t += __shfl_xor(t, 32);
        if (quad == 0) part_l[pbase + m * 16 + l16] = t;
    }
    float* po = part_o + pbase * 64;
    #pragma unroll
    for (int m = 0; m < 2; ++m)
        #pragma unroll
        for (int ct = 0; ct < 4; ++ct)
            *(v4f*)(po + (size_t)(m * 16 + l16) * 64 + ct * 16 + quad * 4) = o[m][ct];
}

// ---------------------------------------------------------------------------
// Combine: sum chunk partials, normalize, transpose, add x, store.
// Grid: (64 i-tiles, 8 batches) x 256 threads.
// ---------------------------------------------------------------------------
__global__ __launch_bounds__(256, 2) void combine_kernel(
    const float* __restrict__ part_o,  // [8][KS][4096][64]
    const float* __restrict__ part_l,  // [8][KS][4096]
    const float* __restrict__ x,       // [8][64][4096]
    float* __restrict__ out,           // [8][64][4096]
    int nchunk)
{
    __shared__ float Of[64 * 65];
    const int tid = threadIdx.x;
    const int b = blockIdx.y;
    const int i0 = blockIdx.x * 64;
    const int row = tid >> 2;          // local n 0..63
    const int seg = tid & 3;           // 16-col segment

    float acc[16];
    #pragma unroll
    for (int k = 0; k < 16; ++k) acc[k] = 0.f;
    float lt = 0.f;

    for (int ch = 0; ch < nchunk; ++ch) {
        const size_t base = (size_t)(b * nchunk + ch) * NTOK + i0 + row;
        lt += part_l[base];
        const float* po = part_o + base * 64 + seg * 16;
        #pragma unroll
        for (int k = 0; k < 4; ++k) {
            float4 v = *(const float4*)(po + k * 4);
            acc[k*4+0] += v.x; acc[k*4+1] += v.y; acc[k*4+2] += v.z; acc[k*4+3] += v.w;
        }
    }
    const float inv = 1.f / lt;
    #pragma unroll
    for (int k = 0; k < 16; ++k) Of[row * 65 + seg * 16 + k] = acc[k] * inv;
    __syncthreads();

    const int c    = tid >> 2;
    const int part = tid & 3;
    const float* xrow = x   + ((size_t)b * CCH + c) * NTOK + i0 + part * 16;
    float*       orow = out + ((size_t)b * CCH + c) * NTOK + i0 + part * 16;
    #pragma unroll
    for (int i4 = 0; i4 < 4; ++i4) {
        float4 xv = *(const float4*)(xrow + i4 * 4);
        float4 ov;
        ov.x = Of[(part * 16 + i4 * 4 + 0) * 65 + c] + xv.x;
        ov.y = Of[(part * 16 + i4 * 4 + 1) * 65 + c] + xv.y;
        ov.z = Of[(part * 16 + i4 * 4 + 2) * 65 + c] + xv.z;
        ov.w = Of[(part * 16 + i4 * 4 + 3) * 65 + c] + xv.w;
        *(float4*)(orow + i4 * 4) = ov;
    }
}

// ---------------------------------------------------------------------------
extern "C" void kernel_launch(void* const* d_in, const int* in_sizes, int n_in,
                              void* d_out, int out_size, void* d_ws, size_t ws_size,
                              hipStream_t stream) {
    const float* x = (const float*)d_in[0];
    const float* w = (const float*)d_in[1];
    float* out = (float*)d_out;

    const size_t xT_elems = (size_t)8 * NTOK * CCH;         // 2M shorts = 4 MB
    unsigned short* xT = (unsigned short*)d_ws;
    unsigned short* sT = xT + xT_elems;
    char* rest = (char*)d_ws + 2 * xT_elems * sizeof(unsigned short);   // +8 MB

    int KS = 4;
    while (KS > 1) {
        size_t need = 2 * xT_elems * sizeof(unsigned short)
                    + (size_t)KS * ((size_t)8 * NTOK * CCH * 4 + (size_t)8 * NTOK * 4);
        if (need <= ws_size) break;
        KS >>= 1;
    }
    float* part_o = (float*)rest;
    float* part_l = (float*)(rest + (size_t)KS * 8 * NTOK * CCH * 4);

    dim3 gp(64, 8);
    prep_kernel<<<gp, 256, 0, stream>>>(x, w, xT, sT);
    dim3 gf(32, KS, 8);
    flash_kernel<<<gf, 256, 0, stream>>>(xT, sT, part_o, part_l, KS, NTOK / KS);
    dim3 gc(64, 8);
    combine_kernel<<<gc, 256, 0, stream>>>(part_o, part_l, x, out, KS);
}

// Round 2
// 128.012 us; speedup vs baseline: 1.0228x; 1.0228x over previous
//
#include <hip/hip_runtime.h>
#include <stdint.h>

// B=8, C=64, N=4096. Flash attention with Q=K=x^T [N,64], V=x^T W [N,64].
// Round 7: single-barrier double-buffered pipeline (round 6) at 4 blocks/CU.
// Pt halved to 8 KB by jt-blocking: the 64-j tile is processed as two 32-j
// halves, each {S-MFMA x8 -> exp/pack -> P-store -> pb-read -> PV x8 with the
// matching V chunk}. Identical op counts to round 5, but P^T holds only 32
// cols -> LDS = Kt[2](16K) + Vt[2](16K) + Pt(8K) = 40 KB; 4 x 40960 = 160 KiB
// exactly. Prefetch(t+1) issued right after the sole per-iter barrier.

#define NTOK 4096
#define CCH  64

typedef float v4f __attribute__((ext_vector_type(4)));
typedef __bf16 v8bf __attribute__((ext_vector_type(8)));
typedef unsigned short v8us __attribute__((ext_vector_type(8)));

__device__ __forceinline__ unsigned short f2bf(float f) {
    union { float f; unsigned int u; } c; c.f = f;
    unsigned int r = c.u + 0x7fffu + ((c.u >> 16) & 1u);   // RNE
    return (unsigned short)(r >> 16);
}

__device__ __forceinline__ v8bf ld8(const unsigned short* p) {
    union { v8us s; v8bf b; } u;
    u.s = *(const v8us*)p;
    return u.b;
}

// pack two f32 -> u32 of (bf16_trunc(a) | bf16_trunc(b)<<16), one v_perm
__device__ __forceinline__ unsigned int pkbf(float a, float b) {
    union { float f; unsigned int u; } ua, ub; ua.f = a; ub.f = b;
    return __builtin_amdgcn_perm(ub.u, ua.u, 0x07060302u);
}

__device__ __forceinline__ float ex2(float x) {
#if __has_builtin(__builtin_amdgcn_exp2f)
    return __builtin_amdgcn_exp2f(x);
#else
    return exp2f(x);
#endif
}

// async global->LDS, 16B per lane; LDS dest = wave-uniform base + lane*16
__device__ __forceinline__ void gload_lds16(const void* g, void* l) {
    __builtin_amdgcn_global_load_lds(
        (const __attribute__((address_space(1))) unsigned int*)g,
        (__attribute__((address_space(3))) unsigned int*)l,
        16, 0, 0);
}

// ---------------------------------------------------------------------------
// Prep: xT[b][n][c] = bf16(x[b][c][n]);  sT[b][d][n] = bf16(sum_c x[b][c][n] W[c][d])
// Grid (64, 8) x 256. Block = 64 tokens. Wave wv owns d-range [wv*16, wv*16+16).
// ---------------------------------------------------------------------------
__global__ __launch_bounds__(256) void prep_kernel(
    const float* __restrict__ x,        // [8][64][4096]
    const float* __restrict__ w,        // [64][64]
    unsigned short* __restrict__ xT,    // [8][4096][64] bf16
    unsigned short* __restrict__ sT)    // [8][64][4096] bf16
{
    __shared__ float Xf[64 * 65];       // [c][n], stride 65 (bank-spread)

    const int tid  = threadIdx.x;
    const int lane = tid & 63;
    const int wv   = __builtin_amdgcn_readfirstlane(tid >> 6);  // wave-uniform
    const int b    = blockIdx.y;
    const int n0   = blockIdx.x * 64;

    // ---- stage x tile [64 c][64 n] f32 into LDS (coalesced global reads) ----
    const float* xb = x + (size_t)b * CCH * NTOK + n0 + lane;
    #pragma unroll
    for (int k = 0; k < 16; ++k) {
        const int c = wv * 16 + k;
        Xf[c * 65 + lane] = xb[(size_t)c * NTOK];
    }
    __syncthreads();

    // ---- write xT[n][c] bf16: thread -> n = tid>>2, c-chunk = (tid&3)*16 ----
    {
        const int n  = tid >> 2;
        const int c0 = (tid & 3) * 16;
        unsigned int pk[8];
        #pragma unroll
        for (int k = 0; k < 8; ++k) {
            const float a = Xf[(c0 + 2 * k) * 65 + n];
            const float c2 = Xf[(c0 + 2 * k + 1) * 65 + n];
            pk[k] = (unsigned int)f2bf(a) | ((unsigned int)f2bf(c2) << 16);
        }
        unsigned short* xtr = xT + ((size_t)b * NTOK + n0 + n) * CCH + c0;
        *(uint4*)(xtr)     = *(uint4*)(pk);
        *(uint4*)(xtr + 8) = *(uint4*)(pk + 4);
    }

    // ---- support: lane's token n0+lane, d in [wv*16, wv*16+16) ----
    float acc[16];
    #pragma unroll
    for (int d = 0; d < 16; ++d) acc[d] = 0.f;

    #pragma unroll 4
    for (int c = 0; c < 64; ++c) {
        const float xc = Xf[c * 65 + lane];
        const float* wr = w + c * 64 + wv * 16;      // scalar address -> s_load
        #pragma unroll
        for (int d = 0; d < 16; ++d) acc[d] = fmaf(xc, wr[d], acc[d]);
    }
    unsigned short* stb = sT + (size_t)b * CCH * NTOK + n0 + lane;
    #pragma unroll
    for (int d = 0; d < 16; ++d)
        stb[(size_t)(wv * 16 + d) * NTOK] = f2bf(acc[d]);    // coalesced
}

// ---------------------------------------------------------------------------
// Flash chunk kernel. Grid: (32 i-tiles, KS chunks, 8 batches) x 256 thr.
// Block = 128 Q rows (32/wave, 2 m-tiles). j-tile = 64, K/V double-buffered.
// S^T = K·Q^T via mfma(K_frag, Q_frag): D[row=j_loc=quad*4+r][col=i_loc=l16].
// Inner loop jt-blocked in two 32-j halves; P^T staged per-half in a 2 KB/wave
// LDS buffer ([32 i][32 j], 4-chunk XOR swizzle). O^T = V^T·P^T accumulated
// across halves. Pipeline per iter: sync (prefetch landed + prev readers done)
// -> issue prefetch(t+1) -> compute(t). Single barrier per iteration.
// ---------------------------------------------------------------------------
__global__ __launch_bounds__(256, 4) void flash_kernel(
    const unsigned short* __restrict__ xT,   // [8][4096][64]
    const unsigned short* __restrict__ sT,   // [8][64][4096]
    float* __restrict__ part_o,              // [8][KS][4096][64]
    float* __restrict__ part_l,              // [8][KS][4096]
    int nchunk, int chunk_len)
{
    __shared__ __align__(16) unsigned short Kt[2][64 * 64];  // 16 KB
    __shared__ __align__(16) unsigned short Vt[2][64 * 64];  // 16 KB
    __shared__ __align__(16) unsigned short Pt[4][32 * 32];  // 8 KB

    const int tid  = threadIdx.x;
    const int w    = tid >> 6;
    const int lane = tid & 63;
    const int quad = lane >> 4;
    const int l16  = lane & 15;
    const int b     = blockIdx.z;
    const int chunk = blockIdx.y;
    const int i0   = blockIdx.x * 128;
    const int irow = i0 + w * 32;
    const int jb   = chunk * chunk_len;

    const unsigned short* xTb = xT + (size_t)b * NTOK * CCH;
    const unsigned short* sTb = sT + (size_t)b * CCH * NTOK;

    // staging geometry: lane stages row (s*32 + srow), swizzled chunk sc
    const int srow = w * 8 + (lane >> 3);          // 0..31
    const int sc   = (lane & 7) ^ (lane >> 3);     // global chunk to fetch

    auto stage = [&](int j0, int bf) {
        unsigned short* kd = Kt[bf] + w * 512;
        unsigned short* vd = Vt[bf] + w * 512;
        gload_lds16(xTb + (size_t)(j0 + srow) * CCH + sc * 8,       kd);
        gload_lds16(xTb + (size_t)(j0 + 32 + srow) * CCH + sc * 8,  kd + 2048);
        gload_lds16(sTb + (size_t)srow * NTOK + j0 + sc * 8,        vd);
        gload_lds16(sTb + (size_t)(32 + srow) * NTOK + j0 + sc * 8, vd + 2048);
    };

    // prologue: issue tile-0 staging before register setup (extra overlap)
    stage(jb, 0);

    // Q fragments (B-operand of S^T): lane holds Q[irow+m*16+l16][quad*8+..]
    v8bf aq0[2], aq1[2];
    #pragma unroll
    for (int m = 0; m < 2; ++m) {
        const unsigned short* qr = xTb + (size_t)(irow + m * 16 + l16) * CCH + quad * 8;
        aq0[m] = ld8(qr);
        aq1[m] = ld8(qr + 32);
    }

    // fixed stabilizer in log2 domain: negm2[m] = -||q_i||^2 * log2(e)
    const float L2E = 1.4426950408889634f;
    float negm2[2];
    #pragma unroll
    for (int m = 0; m < 2; ++m) {
        float msq = 0.f;
        #pragma unroll
        for (int i = 0; i < 8; ++i) {
            float e0 = (float)aq0[m][i], e1 = (float)aq1[m][i];
            msq = fmaf(e0, e0, msq);
            msq = fmaf(e1, e1, msq);
        }
        msq += __shfl_xor(msq, 16);
        msq += __shfl_xor(msq, 32);
        negm2[m] = -msq * L2E;
    }

    v4f o[2][4];        // o[m][ct]: O^T tile rows d=ct*16+quad*4+r, col i=m*16+l16
    #pragma unroll
    for (int m = 0; m < 2; ++m)
        #pragma unroll
        for (int ct = 0; ct < 4; ++ct) { o[m][ct][0]=0.f; o[m][ct][1]=0.f; o[m][ct][2]=0.f; o[m][ct][3]=0.f; }
    float rsum[2] = {0.f, 0.f};

    unsigned short* Pw = Pt[w];
    const int phalf = (quad & 1) * 4;              // 4-short half within chunk
    const int pgq   = quad >> 1;                   // chunk bit from quad
    const int pswz  = l16 & 3;                     // 2-bit chunk XOR (4 chunks/row)

    int cur = 0;
    for (int jj = 0; jj < chunk_len; jj += 64) {
        // tile jj is staged in buf[cur]; rendezvous also proves all waves are
        // done reading buf[cur^1], so it is safe to restage it below.
        __syncthreads();
        if (jj + 64 < chunk_len)
            stage(jb + jj + 64, cur ^ 1);          // prefetch overlaps compute

        const unsigned short* Kc = Kt[cur];
        const unsigned short* Vc = Vt[cur];

        // ---- two 32-j halves: S^T -> exp2 -> P^T store -> pb read -> PV ----
        #pragma unroll
        for (int h = 0; h < 2; ++h) {
            // S-phase for this half: jt = 2h, 2h+1
            #pragma unroll
            for (int jtl = 0; jtl < 2; ++jtl) {
                const int jt   = 2 * h + jtl;
                const int krow = 16 * jt + l16;
                const unsigned short* kb = Kc + krow * 64;
                const int c0 = quad ^ (krow & 7);
                v8bf bk0 = ld8(kb + c0 * 8);
                v8bf bk1 = ld8(kb + (c0 ^ 4) * 8);
                #pragma unroll
                for (int m = 0; m < 2; ++m) {
                    v4f z; z[0]=0.f; z[1]=0.f; z[2]=0.f; z[3]=0.f;
                    z = __builtin_amdgcn_mfma_f32_16x16x32_bf16(bk0, aq0[m], z, 0, 0, 0);
                    z = __builtin_amdgcn_mfma_f32_16x16x32_bf16(bk1, aq1[m], z, 0, 0, 0);
                    const float p0 = ex2(fmaf(z[0], L2E, negm2[m]));
                    const float p1 = ex2(fmaf(z[1], L2E, negm2[m]));
                    const float p2 = ex2(fmaf(z[2], L2E, negm2[m]));
                    const float p3 = ex2(fmaf(z[3], L2E, negm2[m]));
                    rsum[m] += (p0 + p1) + (p2 + p3);
                    uint2 pk; pk.x = pkbf(p0, p1); pk.y = pkbf(p2, p3);
                    // row i = m*16+l16; j_loc = 16*jtl + quad*4 + r
                    //   -> chunk g = 2*jtl + pgq (4 chunks of 8 shorts per row)
                    const int pos = (2 * jtl + pgq) ^ pswz;
                    *(uint2*)(Pw + (m * 16 + l16) * 32 + pos * 8 + phalf) = pk;
                }
            }

            // P^T B-frags for this half (wave-local; lgkmcnt + in-order DS pipe)
            v8bf pb[2];
            #pragma unroll
            for (int m = 0; m < 2; ++m)
                pb[m] = ld8(Pw + (m * 16 + l16) * 32 + (quad ^ pswz) * 8);

            // O^T += V^T[:, half] P^T[half, :]
            #pragma unroll
            for (int ct = 0; ct < 4; ++ct) {
                const int vrow = 16 * ct + l16;
                const unsigned short* vb = Vc + vrow * 64;
                const int cc = (4 * h + quad) ^ (vrow & 7);
                v8bf bv = ld8(vb + cc * 8);
                #pragma unroll
                for (int m = 0; m < 2; ++m)
                    o[m][ct] = __builtin_amdgcn_mfma_f32_16x16x32_bf16(bv, pb[m], o[m][ct], 0, 0, 0);
            }
        }
        cur ^= 1;
    }

    // ---- epilogue ----
    const size_t pbase = (size_t)(b * nchunk + chunk) * NTOK + irow;
    #pragma unroll
    for (int m = 0; m < 2; ++m) {
        float t = rsum[m];
        t += __shfl_xor(t, 16);
        t += __shfl_xor(t, 32);
        if (quad == 0) part_l[pbase + m * 16 + l16] = t;
    }
    float* po = part_o + pbase * 64;
    #pragma unroll
    for (int m = 0; m < 2; ++m)
        #pragma unroll
        for (int ct = 0; ct < 4; ++ct)
            *(v4f*)(po + (size_t)(m * 16 + l16) * 64 + ct * 16 + quad * 4) = o[m][ct];
}

// ---------------------------------------------------------------------------
// Combine: sum chunk partials, normalize, transpose, add x, store.
// Grid: (64 i-tiles, 8 batches) x 256 threads.
// ---------------------------------------------------------------------------
__global__ __launch_bounds__(256, 2) void combine_kernel(
    const float* __restrict__ part_o,  // [8][KS][4096][64]
    const float* __restrict__ part_l,  // [8][KS][4096]
    const float* __restrict__ x,       // [8][64][4096]
    float* __restrict__ out,           // [8][64][4096]
    int nchunk)
{
    __shared__ float Of[64 * 65];
    const int tid = threadIdx.x;
    const int b = blockIdx.y;
    const int i0 = blockIdx.x * 64;
    const int row = tid >> 2;          // local n 0..63
    const int seg = tid & 3;           // 16-col segment

    float acc[16];
    #pragma unroll
    for (int k = 0; k < 16; ++k) acc[k] = 0.f;
    float lt = 0.f;

    for (int ch = 0; ch < nchunk; ++ch) {
        const size_t base = (size_t)(b * nchunk + ch) * NTOK + i0 + row;
        lt += part_l[base];
        const float* po = part_o + base * 64 + seg * 16;
        #pragma unroll
        for (int k = 0; k < 4; ++k) {
            float4 v = *(const float4*)(po + k * 4);
            acc[k*4+0] += v.x; acc[k*4+1] += v.y; acc[k*4+2] += v.z; acc[k*4+3] += v.w;
        }
    }
    const float inv = 1.f / lt;
    #pragma unroll
    for (int k = 0; k < 16; ++k) Of[row * 65 + seg * 16 + k] = acc[k] * inv;
    __syncthreads();

    const int c    = tid >> 2;
    const int part = tid & 3;
    const float* xrow = x   + ((size_t)b * CCH + c) * NTOK + i0 + part * 16;
    float*       orow = out + ((size_t)b * CCH + c) * NTOK + i0 + part * 16;
    #pragma unroll
    for (int i4 = 0; i4 < 4; ++i4) {
        float4 xv = *(const float4*)(xrow + i4 * 4);
        float4 ov;
        ov.x = Of[(part * 16 + i4 * 4 + 0) * 65 + c] + xv.x;
        ov.y = Of[(part * 16 + i4 * 4 + 1) * 65 + c] + xv.y;
        ov.z = Of[(part * 16 + i4 * 4 + 2) * 65 + c] + xv.z;
        ov.w = Of[(part * 16 + i4 * 4 + 3) * 65 + c] + xv.w;
        *(float4*)(orow + i4 * 4) = ov;
    }
}

// ---------------------------------------------------------------------------
extern "C" void kernel_launch(void* const* d_in, const int* in_sizes, int n_in,
                              void* d_out, int out_size, void* d_ws, size_t ws_size,
                              hipStream_t stream) {
    const float* x = (const float*)d_in[0];
    const float* w = (const float*)d_in[1];
    float* out = (float*)d_out;

    const size_t xT_elems = (size_t)8 * NTOK * CCH;         // 2M shorts = 4 MB
    unsigned short* xT = (unsigned short*)d_ws;
    unsigned short* sT = xT + xT_elems;
    char* rest = (char*)d_ws + 2 * xT_elems * sizeof(unsigned short);   // +8 MB

    int KS = 4;
    while (KS > 1) {
        size_t need = 2 * xT_elems * sizeof(unsigned short)
                    + (size_t)KS * ((size_t)8 * NTOK * CCH * 4 + (size_t)8 * NTOK * 4);
        if (need <= ws_size) break;
        KS >>= 1;
    }
    float* part_o = (float*)rest;
    float* part_l = (float*)(rest + (size_t)KS * 8 * NTOK * CCH * 4);

    dim3 gp(64, 8);
    prep_kernel<<<gp, 256, 0, stream>>>(x, w, xT, sT);
    dim3 gf(32, KS, 8);
    flash_kernel<<<gf, 256, 0, stream>>>(xT, sT, part_o, part_l, KS, NTOK / KS);
    dim3 gc(64, 8);
    combine_kernel<<<gc, 256, 0, stream>>>(part_o, part_l, x, out, KS);
}

// Round 4
// 123.664 us; speedup vs baseline: 1.0587x; 1.0352x over previous
//
#include <hip/hip_runtime.h>
#include <stdint.h>

// B=8, C=64, N=4096. Flash attention with Q=K=x^T [N,64], V=x^T W [N,64].
// Round 8b: same as round 8 (Pt bank-conflict fix + f16 partials), with the
// cvt_pkrtz return type corrected to __fp16 ext_vector(2).
// (a) Pt chunk-XOR uses pswz = (l16>>1)&3 — orthogonal to the row-parity bank
// bit ((l16&1)*16 from the 64B row stride). 8 distinct 16B slots / 16 lanes.
// (b) part_o partials stored as f16 via cvt_pkrtz: halves flash write traffic
// and combine read traffic; combine unrolls nchunk==4.

#define NTOK 4096
#define CCH  64

typedef float v4f __attribute__((ext_vector_type(4)));
typedef __bf16 v8bf __attribute__((ext_vector_type(8)));
typedef unsigned short v8us __attribute__((ext_vector_type(8)));
typedef __fp16 v2fp __attribute__((ext_vector_type(2)));
typedef _Float16 v8h __attribute__((ext_vector_type(8)));

__device__ __forceinline__ unsigned short f2bf(float f) {
    union { float f; unsigned int u; } c; c.f = f;
    unsigned int r = c.u + 0x7fffu + ((c.u >> 16) & 1u);   // RNE
    return (unsigned short)(r >> 16);
}

__device__ __forceinline__ v8bf ld8(const unsigned short* p) {
    union { v8us s; v8bf b; } u;
    u.s = *(const v8us*)p;
    return u.b;
}

// pack two f32 -> u32 of (bf16_trunc(a) | bf16_trunc(b)<<16), one v_perm
__device__ __forceinline__ unsigned int pkbf(float a, float b) {
    union { float f; unsigned int u; } ua, ub; ua.f = a; ub.f = b;
    return __builtin_amdgcn_perm(ub.u, ua.u, 0x07060302u);
}

__device__ __forceinline__ float ex2(float x) {
#if __has_builtin(__builtin_amdgcn_exp2f)
    return __builtin_amdgcn_exp2f(x);
#else
    return exp2f(x);
#endif
}

// async global->LDS, 16B per lane; LDS dest = wave-uniform base + lane*16
__device__ __forceinline__ void gload_lds16(const void* g, void* l) {
    __builtin_amdgcn_global_load_lds(
        (const __attribute__((address_space(1))) unsigned int*)g,
        (__attribute__((address_space(3))) unsigned int*)l,
        16, 0, 0);
}

// ---------------------------------------------------------------------------
// Prep: xT[b][n][c] = bf16(x[b][c][n]);  sT[b][d][n] = bf16(sum_c x[b][c][n] W[c][d])
// Grid (64, 8) x 256. Block = 64 tokens. Wave wv owns d-range [wv*16, wv*16+16).
// ---------------------------------------------------------------------------
__global__ __launch_bounds__(256) void prep_kernel(
    const float* __restrict__ x,        // [8][64][4096]
    const float* __restrict__ w,        // [64][64]
    unsigned short* __restrict__ xT,    // [8][4096][64] bf16
    unsigned short* __restrict__ sT)    // [8][64][4096] bf16
{
    __shared__ float Xf[64 * 65];       // [c][n], stride 65 (bank-spread)

    const int tid  = threadIdx.x;
    const int lane = tid & 63;
    const int wv   = __builtin_amdgcn_readfirstlane(tid >> 6);  // wave-uniform
    const int b    = blockIdx.y;
    const int n0   = blockIdx.x * 64;

    // ---- stage x tile [64 c][64 n] f32 into LDS (coalesced global reads) ----
    const float* xb = x + (size_t)b * CCH * NTOK + n0 + lane;
    #pragma unroll
    for (int k = 0; k < 16; ++k) {
        const int c = wv * 16 + k;
        Xf[c * 65 + lane] = xb[(size_t)c * NTOK];
    }
    __syncthreads();

    // ---- write xT[n][c] bf16: thread -> n = tid>>2, c-chunk = (tid&3)*16 ----
    {
        const int n  = tid >> 2;
        const int c0 = (tid & 3) * 16;
        unsigned int pk[8];
        #pragma unroll
        for (int k = 0; k < 8; ++k) {
            const float a = Xf[(c0 + 2 * k) * 65 + n];
            const float c2 = Xf[(c0 + 2 * k + 1) * 65 + n];
            pk[k] = (unsigned int)f2bf(a) | ((unsigned int)f2bf(c2) << 16);
        }
        unsigned short* xtr = xT + ((size_t)b * NTOK + n0 + n) * CCH + c0;
        *(uint4*)(xtr)     = *(uint4*)(pk);
        *(uint4*)(xtr + 8) = *(uint4*)(pk + 4);
    }

    // ---- support: lane's token n0+lane, d in [wv*16, wv*16+16) ----
    float acc[16];
    #pragma unroll
    for (int d = 0; d < 16; ++d) acc[d] = 0.f;

    #pragma unroll 4
    for (int c = 0; c < 64; ++c) {
        const float xc = Xf[c * 65 + lane];
        const float* wr = w + c * 64 + wv * 16;      // scalar address -> s_load
        #pragma unroll
        for (int d = 0; d < 16; ++d) acc[d] = fmaf(xc, wr[d], acc[d]);
    }
    unsigned short* stb = sT + (size_t)b * CCH * NTOK + n0 + lane;
    #pragma unroll
    for (int d = 0; d < 16; ++d)
        stb[(size_t)(wv * 16 + d) * NTOK] = f2bf(acc[d]);    // coalesced
}

// ---------------------------------------------------------------------------
// Flash chunk kernel. Grid: (32 i-tiles, KS chunks, 8 batches) x 256 thr.
// Block = 128 Q rows (32/wave, 2 m-tiles). j-tile = 64, K/V double-buffered.
// S^T = K·Q^T via mfma(K_frag, Q_frag): D[row=j_loc=quad*4+r][col=i_loc=l16].
// Inner loop jt-blocked in two 32-j halves; P^T staged per-half in a 2 KB/wave
// LDS buffer ([32 i][32 j], chunk XOR = (l16>>1)&3 — orthogonal to row-parity
// bank bit). O^T = V^T·P^T accumulated across halves. Pipeline per iter:
// sync -> issue prefetch(t+1) -> compute(t). Single barrier per iteration.
// Output partials stored as f16 (cvt_pkrtz).
// ---------------------------------------------------------------------------
__global__ __launch_bounds__(256, 4) void flash_kernel(
    const unsigned short* __restrict__ xT,   // [8][4096][64]
    const unsigned short* __restrict__ sT,   // [8][64][4096]
    unsigned short* __restrict__ part_o,     // [8][KS][4096][64] f16
    float* __restrict__ part_l,              // [8][KS][4096]
    int nchunk, int chunk_len)
{
    __shared__ __align__(16) unsigned short Kt[2][64 * 64];  // 16 KB
    __shared__ __align__(16) unsigned short Vt[2][64 * 64];  // 16 KB
    __shared__ __align__(16) unsigned short Pt[4][32 * 32];  // 8 KB

    const int tid  = threadIdx.x;
    const int w    = tid >> 6;
    const int lane = tid & 63;
    const int quad = lane >> 4;
    const int l16  = lane & 15;
    const int b     = blockIdx.z;
    const int chunk = blockIdx.y;
    const int i0   = blockIdx.x * 128;
    const int irow = i0 + w * 32;
    const int jb   = chunk * chunk_len;

    const unsigned short* xTb = xT + (size_t)b * NTOK * CCH;
    const unsigned short* sTb = sT + (size_t)b * CCH * NTOK;

    // staging geometry: lane stages row (s*32 + srow), swizzled chunk sc
    const int srow = w * 8 + (lane >> 3);          // 0..31
    const int sc   = (lane & 7) ^ (lane >> 3);     // global chunk to fetch

    auto stage = [&](int j0, int bf) {
        unsigned short* kd = Kt[bf] + w * 512;
        unsigned short* vd = Vt[bf] + w * 512;
        gload_lds16(xTb + (size_t)(j0 + srow) * CCH + sc * 8,       kd);
        gload_lds16(xTb + (size_t)(j0 + 32 + srow) * CCH + sc * 8,  kd + 2048);
        gload_lds16(sTb + (size_t)srow * NTOK + j0 + sc * 8,        vd);
        gload_lds16(sTb + (size_t)(32 + srow) * NTOK + j0 + sc * 8, vd + 2048);
    };

    // prologue: issue tile-0 staging before register setup (extra overlap)
    stage(jb, 0);

    // Q fragments (B-operand of S^T): lane holds Q[irow+m*16+l16][quad*8+..]
    v8bf aq0[2], aq1[2];
    #pragma unroll
    for (int m = 0; m < 2; ++m) {
        const unsigned short* qr = xTb + (size_t)(irow + m * 16 + l16) * CCH + quad * 8;
        aq0[m] = ld8(qr);
        aq1[m] = ld8(qr + 32);
    }

    // fixed stabilizer in log2 domain: negm2[m] = -||q_i||^2 * log2(e)
    const float L2E = 1.4426950408889634f;
    float negm2[2];
    #pragma unroll
    for (int m = 0; m < 2; ++m) {
        float msq = 0.f;
        #pragma unroll
        for (int i = 0; i < 8; ++i) {
            float e0 = (float)aq0[m][i], e1 = (float)aq1[m][i];
            msq = fmaf(e0, e0, msq);
            msq = fmaf(e1, e1, msq);
        }
        msq += __shfl_xor(msq, 16);
        msq += __shfl_xor(msq, 32);
        negm2[m] = -msq * L2E;
    }

    v4f o[2][4];        // o[m][ct]: O^T tile rows d=ct*16+quad*4+r, col i=m*16+l16
    #pragma unroll
    for (int m = 0; m < 2; ++m)
        #pragma unroll
        for (int ct = 0; ct < 4; ++ct) { o[m][ct][0]=0.f; o[m][ct][1]=0.f; o[m][ct][2]=0.f; o[m][ct][3]=0.f; }
    float rsum[2] = {0.f, 0.f};

    unsigned short* Pw = Pt[w];
    const int phalf = (quad & 1) * 4;              // 4-short half within chunk
    const int pgq   = quad >> 1;                   // chunk bit from quad
    const int pswz  = (l16 >> 1) & 3;              // chunk XOR, bits 1:2 of row
                                                   // (bit 0 is the bank-parity bit)

    int cur = 0;
    for (int jj = 0; jj < chunk_len; jj += 64) {
        // tile jj is staged in buf[cur]; rendezvous also proves all waves are
        // done reading buf[cur^1], so it is safe to restage it below.
        __syncthreads();
        if (jj + 64 < chunk_len)
            stage(jb + jj + 64, cur ^ 1);          // prefetch overlaps compute

        const unsigned short* Kc = Kt[cur];
        const unsigned short* Vc = Vt[cur];

        // ---- two 32-j halves: S^T -> exp2 -> P^T store -> pb read -> PV ----
        #pragma unroll
        for (int h = 0; h < 2; ++h) {
            // S-phase for this half: jt = 2h, 2h+1
            #pragma unroll
            for (int jtl = 0; jtl < 2; ++jtl) {
                const int jt   = 2 * h + jtl;
                const int krow = 16 * jt + l16;
                const unsigned short* kb = Kc + krow * 64;
                const int c0 = quad ^ (krow & 7);
                v8bf bk0 = ld8(kb + c0 * 8);
                v8bf bk1 = ld8(kb + (c0 ^ 4) * 8);
                #pragma unroll
                for (int m = 0; m < 2; ++m) {
                    v4f z; z[0]=0.f; z[1]=0.f; z[2]=0.f; z[3]=0.f;
                    z = __builtin_amdgcn_mfma_f32_16x16x32_bf16(bk0, aq0[m], z, 0, 0, 0);
                    z = __builtin_amdgcn_mfma_f32_16x16x32_bf16(bk1, aq1[m], z, 0, 0, 0);
                    const float p0 = ex2(fmaf(z[0], L2E, negm2[m]));
                    const float p1 = ex2(fmaf(z[1], L2E, negm2[m]));
                    const float p2 = ex2(fmaf(z[2], L2E, negm2[m]));
                    const float p3 = ex2(fmaf(z[3], L2E, negm2[m]));
                    rsum[m] += (p0 + p1) + (p2 + p3);
                    uint2 pk; pk.x = pkbf(p0, p1); pk.y = pkbf(p2, p3);
                    // row i = m*16+l16; j_loc = 16*jtl + quad*4 + r
                    //   -> chunk g = 2*jtl + pgq (4 chunks of 8 shorts per row)
                    const int pos = (2 * jtl + pgq) ^ pswz;
                    *(uint2*)(Pw + (m * 16 + l16) * 32 + pos * 8 + phalf) = pk;
                }
            }

            // P^T B-frags for this half (wave-local; lgkmcnt + in-order DS pipe)
            v8bf pb[2];
            #pragma unroll
            for (int m = 0; m < 2; ++m)
                pb[m] = ld8(Pw + (m * 16 + l16) * 32 + (quad ^ pswz) * 8);

            // O^T += V^T[:, half] P^T[half, :]
            #pragma unroll
            for (int ct = 0; ct < 4; ++ct) {
                const int vrow = 16 * ct + l16;
                const unsigned short* vb = Vc + vrow * 64;
                const int cc = (4 * h + quad) ^ (vrow & 7);
                v8bf bv = ld8(vb + cc * 8);
                #pragma unroll
                for (int m = 0; m < 2; ++m)
                    o[m][ct] = __builtin_amdgcn_mfma_f32_16x16x32_bf16(bv, pb[m], o[m][ct], 0, 0, 0);
            }
        }
        cur ^= 1;
    }

    // ---- epilogue: f16 partials ----
    const size_t pbase = (size_t)(b * nchunk + chunk) * NTOK + irow;
    #pragma unroll
    for (int m = 0; m < 2; ++m) {
        float t = rsum[m];
        t += __shfl_xor(t, 16);
        t += __shfl_xor(t, 32);
        if (quad == 0) part_l[pbase + m * 16 + l16] = t;
    }
    unsigned short* po = part_o + pbase * 64;
    #pragma unroll
    for (int m = 0; m < 2; ++m)
        #pragma unroll
        for (int ct = 0; ct < 4; ++ct) {
            union { struct { v2fp a, b; } h; uint2 u; } cv;
            cv.h.a = __builtin_amdgcn_cvt_pkrtz(o[m][ct][0], o[m][ct][1]);
            cv.h.b = __builtin_amdgcn_cvt_pkrtz(o[m][ct][2], o[m][ct][3]);
            *(uint2*)(po + (size_t)(m * 16 + l16) * 64 + ct * 16 + quad * 4) = cv.u;
        }
}

// ---------------------------------------------------------------------------
// Combine: sum f16 chunk partials, normalize, transpose, add x, store.
// Grid: (64 i-tiles, 8 batches) x 256 threads. nchunk==4 path fully unrolled.
// ---------------------------------------------------------------------------
__global__ __launch_bounds__(256) void combine_kernel(
    const unsigned short* __restrict__ part_o,  // [8][KS][4096][64] f16
    const float* __restrict__ part_l,           // [8][KS][4096]
    const float* __restrict__ x,                // [8][64][4096]
    float* __restrict__ out,                    // [8][64][4096]
    int nchunk)
{
    __shared__ float Of[64 * 65];
    const int tid = threadIdx.x;
    const int b = blockIdx.y;
    const int i0 = blockIdx.x * 64;
    const int row = tid >> 2;          // local n 0..63
    const int seg = tid & 3;           // 16-col segment

    float acc[16];
    #pragma unroll
    for (int k = 0; k < 16; ++k) acc[k] = 0.f;
    float lt = 0.f;

    auto body = [&](int ch) {
        const size_t base = (size_t)(b * nchunk + ch) * NTOK + i0 + row;
        lt += part_l[base];
        const unsigned short* po = part_o + base * 64 + seg * 16;
        v8h a = *(const v8h*)(po);
        v8h c2 = *(const v8h*)(po + 8);
        #pragma unroll
        for (int k = 0; k < 8; ++k) {
            acc[k]     += (float)a[k];
            acc[8 + k] += (float)c2[k];
        }
    };
    if (nchunk == 4) { body(0); body(1); body(2); body(3); }
    else { for (int ch = 0; ch < nchunk; ++ch) body(ch); }

    const float inv = 1.f / lt;
    #pragma unroll
    for (int k = 0; k < 16; ++k) Of[row * 65 + seg * 16 + k] = acc[k] * inv;
    __syncthreads();

    const int c    = tid >> 2;
    const int part = tid & 3;
    const float* xrow = x   + ((size_t)b * CCH + c) * NTOK + i0 + part * 16;
    float*       orow = out + ((size_t)b * CCH + c) * NTOK + i0 + part * 16;
    #pragma unroll
    for (int i4 = 0; i4 < 4; ++i4) {
        float4 xv = *(const float4*)(xrow + i4 * 4);
        float4 ov;
        ov.x = Of[(part * 16 + i4 * 4 + 0) * 65 + c] + xv.x;
        ov.y = Of[(part * 16 + i4 * 4 + 1) * 65 + c] + xv.y;
        ov.z = Of[(part * 16 + i4 * 4 + 2) * 65 + c] + xv.z;
        ov.w = Of[(part * 16 + i4 * 4 + 3) * 65 + c] + xv.w;
        *(float4*)(orow + i4 * 4) = ov;
    }
}

// ---------------------------------------------------------------------------
extern "C" void kernel_launch(void* const* d_in, const int* in_sizes, int n_in,
                              void* d_out, int out_size, void* d_ws, size_t ws_size,
                              hipStream_t stream) {
    const float* x = (const float*)d_in[0];
    const float* w = (const float*)d_in[1];
    float* out = (float*)d_out;

    const size_t xT_elems = (size_t)8 * NTOK * CCH;         // 2M shorts = 4 MB
    unsigned short* xT = (unsigned short*)d_ws;
    unsigned short* sT = xT + xT_elems;
    char* rest = (char*)d_ws + 2 * xT_elems * sizeof(unsigned short);   // +8 MB

    int KS = 4;
    while (KS > 1) {
        size_t need = 2 * xT_elems * sizeof(unsigned short)
                    + (size_t)KS * ((size_t)8 * NTOK * CCH * 2 + (size_t)8 * NTOK * 4);
        if (need <= ws_size) break;
        KS >>= 1;
    }
    unsigned short* part_o = (unsigned short*)rest;
    float* part_l = (float*)(rest + (size_t)KS * 8 * NTOK * CCH * 2);

    dim3 gp(64, 8);
    prep_kernel<<<gp, 256, 0, stream>>>(x, w, xT, sT);
    dim3 gf(32, KS, 8);
    flash_kernel<<<gf, 256, 0, stream>>>(xT, sT, part_o, part_l, KS, NTOK / KS);
    dim3 gc(64, 8);
    combine_kernel<<<gc, 256, 0, stream>>>(part_o, part_l, x, out, KS);
}

// Round 5
// 119.342 us; speedup vs baseline: 1.0971x; 1.0362x over previous
//
#include <hip/hip_runtime.h>
#include <stdint.h>

// B=8, C=64, N=4096. Flash attention with Q=K=x^T [N,64], V=x^T W [N,64].
// Round 9: P^T never touches LDS. The K-staging permutes tokens so that the
// S^T C-layout (lane quad q holds rows 4q+r of each 16-row subtile) lines up
// with the PV B-frag layout (lane quad q needs k=8q..8q+7): physical K row
// p = 32h+16jtl+4a+r holds token 32h+8a+4jtl+r. Then lane q's S outputs for
// the half are exactly tokens 32h+8q..8q+7, and pb[m] = {pkx0,pky0,pkx1,pky1}
// is lane-local — PV consumes packed exp results straight from registers.
// Removes 16 ds_write + 8 ds_read_b128 + 2 lgkmcnt syncs per iter and the
// 8 KB Pt buffer (LDS 40->32 KB). Physical LDS access patterns (staging,
// K-read chunk XOR, V-read) are byte-identical to the measured-conflict-free
// round-8 patterns. Softmax sums are token-permutation-invariant.

#define NTOK 4096
#define CCH  64

typedef float v4f __attribute__((ext_vector_type(4)));
typedef __bf16 v8bf __attribute__((ext_vector_type(8)));
typedef unsigned short v8us __attribute__((ext_vector_type(8)));
typedef __fp16 v2fp __attribute__((ext_vector_type(2)));
typedef _Float16 v8h __attribute__((ext_vector_type(8)));

__device__ __forceinline__ unsigned short f2bf(float f) {
    union { float f; unsigned int u; } c; c.f = f;
    unsigned int r = c.u + 0x7fffu + ((c.u >> 16) & 1u);   // RNE
    return (unsigned short)(r >> 16);
}

__device__ __forceinline__ v8bf ld8(const unsigned short* p) {
    union { v8us s; v8bf b; } u;
    u.s = *(const v8us*)p;
    return u.b;
}

// pack two f32 -> u32 of (bf16_trunc(a) | bf16_trunc(b)<<16), one v_perm
__device__ __forceinline__ unsigned int pkbf(float a, float b) {
    union { float f; unsigned int u; } ua, ub; ua.f = a; ub.f = b;
    return __builtin_amdgcn_perm(ub.u, ua.u, 0x07060302u);
}

__device__ __forceinline__ float ex2(float x) {
#if __has_builtin(__builtin_amdgcn_exp2f)
    return __builtin_amdgcn_exp2f(x);
#else
    return exp2f(x);
#endif
}

// async global->LDS, 16B per lane; LDS dest = wave-uniform base + lane*16
__device__ __forceinline__ void gload_lds16(const void* g, void* l) {
    __builtin_amdgcn_global_load_lds(
        (const __attribute__((address_space(1))) unsigned int*)g,
        (__attribute__((address_space(3))) unsigned int*)l,
        16, 0, 0);
}

// ---------------------------------------------------------------------------
// Prep: xT[b][n][c] = bf16(x[b][c][n]);  sT[b][d][n] = bf16(sum_c x[b][c][n] W[c][d])
// Grid (64, 8) x 256. Block = 64 tokens. Wave wv owns d-range [wv*16, wv*16+16).
// ---------------------------------------------------------------------------
__global__ __launch_bounds__(256) void prep_kernel(
    const float* __restrict__ x,        // [8][64][4096]
    const float* __restrict__ w,        // [64][64]
    unsigned short* __restrict__ xT,    // [8][4096][64] bf16
    unsigned short* __restrict__ sT)    // [8][64][4096] bf16
{
    __shared__ float Xf[64 * 65];       // [c][n], stride 65 (bank-spread)

    const int tid  = threadIdx.x;
    const int lane = tid & 63;
    const int wv   = __builtin_amdgcn_readfirstlane(tid >> 6);  // wave-uniform
    const int b    = blockIdx.y;
    const int n0   = blockIdx.x * 64;

    // ---- stage x tile [64 c][64 n] f32 into LDS (coalesced global reads) ----
    const float* xb = x + (size_t)b * CCH * NTOK + n0 + lane;
    #pragma unroll
    for (int k = 0; k < 16; ++k) {
        const int c = wv * 16 + k;
        Xf[c * 65 + lane] = xb[(size_t)c * NTOK];
    }
    __syncthreads();

    // ---- write xT[n][c] bf16: thread -> n = tid>>2, c-chunk = (tid&3)*16 ----
    {
        const int n  = tid >> 2;
        const int c0 = (tid & 3) * 16;
        unsigned int pk[8];
        #pragma unroll
        for (int k = 0; k < 8; ++k) {
            const float a = Xf[(c0 + 2 * k) * 65 + n];
            const float c2 = Xf[(c0 + 2 * k + 1) * 65 + n];
            pk[k] = (unsigned int)f2bf(a) | ((unsigned int)f2bf(c2) << 16);
        }
        unsigned short* xtr = xT + ((size_t)b * NTOK + n0 + n) * CCH + c0;
        *(uint4*)(xtr)     = *(uint4*)(pk);
        *(uint4*)(xtr + 8) = *(uint4*)(pk + 4);
    }

    // ---- support: lane's token n0+lane, d in [wv*16, wv*16+16) ----
    float acc[16];
    #pragma unroll
    for (int d = 0; d < 16; ++d) acc[d] = 0.f;

    #pragma unroll 4
    for (int c = 0; c < 64; ++c) {
        const float xc = Xf[c * 65 + lane];
        const float* wr = w + c * 64 + wv * 16;      // scalar address -> s_load
        #pragma unroll
        for (int d = 0; d < 16; ++d) acc[d] = fmaf(xc, wr[d], acc[d]);
    }
    unsigned short* stb = sT + (size_t)b * CCH * NTOK + n0 + lane;
    #pragma unroll
    for (int d = 0; d < 16; ++d)
        stb[(size_t)(wv * 16 + d) * NTOK] = f2bf(acc[d]);    // coalesced
}

// ---------------------------------------------------------------------------
// Flash chunk kernel. Grid: (32 i-tiles, KS chunks, 8 batches) x 256 thr.
// Block = 128 Q rows (32/wave, 2 m-tiles). j-tile = 64, K/V double-buffered.
// S^T = K·Q^T via mfma(K_frag, Q_frag): D[row=4q+r][col=i_loc=l16], where the
// token behind row p of subtile jt=2h+jtl is permuted at staging (see t(p)
// below) so each lane's S outputs are the 8 consecutive tokens its PV B-frag
// needs. PV: O^T += V^T P^T with pb built in-register from packed exp results.
// Pipeline per iter: sync -> issue prefetch(t+1) -> compute(t); one barrier.
// Output partials stored as f16 (cvt_pkrtz).
// ---------------------------------------------------------------------------
__global__ __launch_bounds__(256, 4) void flash_kernel(
    const unsigned short* __restrict__ xT,   // [8][4096][64]
    const unsigned short* __restrict__ sT,   // [8][64][4096]
    unsigned short* __restrict__ part_o,     // [8][KS][4096][64] f16
    float* __restrict__ part_l,              // [8][KS][4096]
    int nchunk, int chunk_len)
{
    __shared__ __align__(16) unsigned short Kt[2][64 * 64];  // 16 KB
    __shared__ __align__(16) unsigned short Vt[2][64 * 64];  // 16 KB

    const int tid  = threadIdx.x;
    const int w    = tid >> 6;
    const int lane = tid & 63;
    const int quad = lane >> 4;
    const int l16  = lane & 15;
    const int b     = blockIdx.z;
    const int chunk = blockIdx.y;
    const int i0   = blockIdx.x * 128;
    const int irow = i0 + w * 32;
    const int jb   = chunk * chunk_len;

    const unsigned short* xTb = xT + (size_t)b * NTOK * CCH;
    const unsigned short* sTb = sT + (size_t)b * CCH * NTOK;

    // staging geometry: lane stages physical row (s*32 + srow), swizzled chunk
    const int srow = w * 8 + (lane >> 3);          // 0..31
    const int sc   = (lane & 7) ^ (lane >> 3);     // global chunk to fetch
    // token permutation for K rows: physical p = 32h+16jtl+4a+r holds token
    // t(p) = 32h+8a+4jtl+r  (so lane quad q's S rows = tokens 8q..8q+7 per half)
    const int ksrow = 8 * ((srow & 12) >> 2) + 4 * ((srow >> 4) & 1) + (srow & 3);
    // t(srow+32) = 32 + t(srow)

    auto stage = [&](int j0, int bf) {
        unsigned short* kd = Kt[bf] + w * 512;
        unsigned short* vd = Vt[bf] + w * 512;
        gload_lds16(xTb + (size_t)(j0 + ksrow) * CCH + sc * 8,       kd);
        gload_lds16(xTb + (size_t)(j0 + 32 + ksrow) * CCH + sc * 8,  kd + 2048);
        gload_lds16(sTb + (size_t)srow * NTOK + j0 + sc * 8,        vd);
        gload_lds16(sTb + (size_t)(32 + srow) * NTOK + j0 + sc * 8, vd + 2048);
    };

    // prologue: issue tile-0 staging before register setup (extra overlap)
    stage(jb, 0);

    // Q fragments (B-operand of S^T): lane holds Q[irow+m*16+l16][quad*8+..]
    v8bf aq0[2], aq1[2];
    #pragma unroll
    for (int m = 0; m < 2; ++m) {
        const unsigned short* qr = xTb + (size_t)(irow + m * 16 + l16) * CCH + quad * 8;
        aq0[m] = ld8(qr);
        aq1[m] = ld8(qr + 32);
    }

    // fixed stabilizer in log2 domain: negm2[m] = -||q_i||^2 * log2(e)
    const float L2E = 1.4426950408889634f;
    float negm2[2];
    #pragma unroll
    for (int m = 0; m < 2; ++m) {
        float msq = 0.f;
        #pragma unroll
        for (int i = 0; i < 8; ++i) {
            float e0 = (float)aq0[m][i], e1 = (float)aq1[m][i];
            msq = fmaf(e0, e0, msq);
            msq = fmaf(e1, e1, msq);
        }
        msq += __shfl_xor(msq, 16);
        msq += __shfl_xor(msq, 32);
        negm2[m] = -msq * L2E;
    }

    v4f o[2][4];        // o[m][ct]: O^T tile rows d=ct*16+quad*4+r, col i=m*16+l16
    #pragma unroll
    for (int m = 0; m < 2; ++m)
        #pragma unroll
        for (int ct = 0; ct < 4; ++ct) { o[m][ct][0]=0.f; o[m][ct][1]=0.f; o[m][ct][2]=0.f; o[m][ct][3]=0.f; }
    float rsum[2] = {0.f, 0.f};

    int cur = 0;
    for (int jj = 0; jj < chunk_len; jj += 64) {
        // tile jj is staged in buf[cur]; rendezvous also proves all waves are
        // done reading buf[cur^1], so it is safe to restage it below.
        __syncthreads();
        if (jj + 64 < chunk_len)
            stage(jb + jj + 64, cur ^ 1);          // prefetch overlaps compute

        const unsigned short* Kc = Kt[cur];
        const unsigned short* Vc = Vt[cur];

        // ---- two 32-token halves: S^T -> exp2 -> in-register pb -> PV ----
        #pragma unroll
        for (int h = 0; h < 2; ++h) {
            uint2 pk[2][2];   // [m][jtl]: packed bf16 exp results
            #pragma unroll
            for (int jtl = 0; jtl < 2; ++jtl) {
                const int krow = 32 * h + 16 * jtl + l16;    // physical row
                const unsigned short* kb = Kc + krow * 64;
                const int c0 = quad ^ (krow & 7);
                v8bf bk0 = ld8(kb + c0 * 8);
                v8bf bk1 = ld8(kb + (c0 ^ 4) * 8);
                #pragma unroll
                for (int m = 0; m < 2; ++m) {
                    v4f z; z[0]=0.f; z[1]=0.f; z[2]=0.f; z[3]=0.f;
                    z = __builtin_amdgcn_mfma_f32_16x16x32_bf16(bk0, aq0[m], z, 0, 0, 0);
                    z = __builtin_amdgcn_mfma_f32_16x16x32_bf16(bk1, aq1[m], z, 0, 0, 0);
                    // lane (quad,l16): z[r] = S^T[token 32h+8q+4jtl+r][i=m*16+l16]
                    const float p0 = ex2(fmaf(z[0], L2E, negm2[m]));
                    const float p1 = ex2(fmaf(z[1], L2E, negm2[m]));
                    const float p2 = ex2(fmaf(z[2], L2E, negm2[m]));
                    const float p3 = ex2(fmaf(z[3], L2E, negm2[m]));
                    rsum[m] += (p0 + p1) + (p2 + p3);
                    pk[m][jtl].x = pkbf(p0, p1);
                    pk[m][jtl].y = pkbf(p2, p3);
                }
            }

            // lane-local PV B-frags: element e = 4*jtl + r -> token 32h+8q+e
            union { unsigned int u[4]; v8bf b; } pb[2];
            #pragma unroll
            for (int m = 0; m < 2; ++m) {
                pb[m].u[0] = pk[m][0].x; pb[m].u[1] = pk[m][0].y;
                pb[m].u[2] = pk[m][1].x; pb[m].u[3] = pk[m][1].y;
            }

            // O^T += V^T[:, tokens 32h..32h+31] P^T[those tokens, :]
            #pragma unroll
            for (int ct = 0; ct < 4; ++ct) {
                const int vrow = 16 * ct + l16;
                const unsigned short* vb = Vc + vrow * 64;
                const int cc = (4 * h + quad) ^ (vrow & 7);
                v8bf bv = ld8(vb + cc * 8);
                #pragma unroll
                for (int m = 0; m < 2; ++m)
                    o[m][ct] = __builtin_amdgcn_mfma_f32_16x16x32_bf16(bv, pb[m].b, o[m][ct], 0, 0, 0);
            }
        }
        cur ^= 1;
    }

    // ---- epilogue: f16 partials ----
    const size_t pbase = (size_t)(b * nchunk + chunk) * NTOK + irow;
    #pragma unroll
    for (int m = 0; m < 2; ++m) {
        float t = rsum[m];
        t += __shfl_xor(t, 16);
        t += __shfl_xor(t, 32);
        if (quad == 0) part_l[pbase + m * 16 + l16] = t;
    }
    unsigned short* po = part_o + pbase * 64;
    #pragma unroll
    for (int m = 0; m < 2; ++m)
        #pragma unroll
        for (int ct = 0; ct < 4; ++ct) {
            union { struct { v2fp a, b; } h; uint2 u; } cv;
            cv.h.a = __builtin_amdgcn_cvt_pkrtz(o[m][ct][0], o[m][ct][1]);
            cv.h.b = __builtin_amdgcn_cvt_pkrtz(o[m][ct][2], o[m][ct][3]);
            *(uint2*)(po + (size_t)(m * 16 + l16) * 64 + ct * 16 + quad * 4) = cv.u;
        }
}

// ---------------------------------------------------------------------------
// Combine: sum f16 chunk partials, normalize, transpose, add x, store.
// Grid: (64 i-tiles, 8 batches) x 256 threads. nchunk==4 path fully unrolled.
// ---------------------------------------------------------------------------
__global__ __launch_bounds__(256) void combine_kernel(
    const unsigned short* __restrict__ part_o,  // [8][KS][4096][64] f16
    const float* __restrict__ part_l,           // [8][KS][4096]
    const float* __restrict__ x,                // [8][64][4096]
    float* __restrict__ out,                    // [8][64][4096]
    int nchunk)
{
    __shared__ float Of[64 * 65];
    const int tid = threadIdx.x;
    const int b = blockIdx.y;
    const int i0 = blockIdx.x * 64;
    const int row = tid >> 2;          // local n 0..63
    const int seg = tid & 3;           // 16-col segment

    float acc[16];
    #pragma unroll
    for (int k = 0; k < 16; ++k) acc[k] = 0.f;
    float lt = 0.f;

    auto body = [&](int ch) {
        const size_t base = (size_t)(b * nchunk + ch) * NTOK + i0 + row;
        lt += part_l[base];
        const unsigned short* po = part_o + base * 64 + seg * 16;
        v8h a = *(const v8h*)(po);
        v8h c2 = *(const v8h*)(po + 8);
        #pragma unroll
        for (int k = 0; k < 8; ++k) {
            acc[k]     += (float)a[k];
            acc[8 + k] += (float)c2[k];
        }
    };
    if (nchunk == 4) { body(0); body(1); body(2); body(3); }
    else { for (int ch = 0; ch < nchunk; ++ch) body(ch); }

    const float inv = 1.f / lt;
    #pragma unroll
    for (int k = 0; k < 16; ++k) Of[row * 65 + seg * 16 + k] = acc[k] * inv;
    __syncthreads();

    const int c    = tid >> 2;
    const int part = tid & 3;
    const float* xrow = x   + ((size_t)b * CCH + c) * NTOK + i0 + part * 16;
    float*       orow = out + ((size_t)b * CCH + c) * NTOK + i0 + part * 16;
    #pragma unroll
    for (int i4 = 0; i4 < 4; ++i4) {
        float4 xv = *(const float4*)(xrow + i4 * 4);
        float4 ov;
        ov.x = Of[(part * 16 + i4 * 4 + 0) * 65 + c] + xv.x;
        ov.y = Of[(part * 16 + i4 * 4 + 1) * 65 + c] + xv.y;
        ov.z = Of[(part * 16 + i4 * 4 + 2) * 65 + c] + xv.z;
        ov.w = Of[(part * 16 + i4 * 4 + 3) * 65 + c] + xv.w;
        *(float4*)(orow + i4 * 4) = ov;
    }
}

// ---------------------------------------------------------------------------
extern "C" void kernel_launch(void* const* d_in, const int* in_sizes, int n_in,
                              void* d_out, int out_size, void* d_ws, size_t ws_size,
                              hipStream_t stream) {
    const float* x = (const float*)d_in[0];
    const float* w = (const float*)d_in[1];
    float* out = (float*)d_out;

    const size_t xT_elems = (size_t)8 * NTOK * CCH;         // 2M shorts = 4 MB
    unsigned short* xT = (unsigned short*)d_ws;
    unsigned short* sT = xT + xT_elems;
    char* rest = (char*)d_ws + 2 * xT_elems * sizeof(unsigned short);   // +8 MB

    int KS = 4;
    while (KS > 1) {
        size_t need = 2 * xT_elems * sizeof(unsigned short)
                    + (size_t)KS * ((size_t)8 * NTOK * CCH * 2 + (size_t)8 * NTOK * 4);
        if (need <= ws_size) break;
        KS >>= 1;
    }
    unsigned short* part_o = (unsigned short*)rest;
    float* part_l = (float*)(rest + (size_t)KS * 8 * NTOK * CCH * 2);

    dim3 gp(64, 8);
    prep_kernel<<<gp, 256, 0, stream>>>(x, w, xT, sT);
    dim3 gf(32, KS, 8);
    flash_kernel<<<gf, 256, 0, stream>>>(xT, sT, part_o, part_l, KS, NTOK / KS);
    dim3 gc(64, 8);
    combine_kernel<<<gc, 256, 0, stream>>>(part_o, part_l, x, out, KS);
}